// Round 8
// baseline (540.680 us; speedup 1.0000x reference)
//
#include <hip/hip_runtime.h>

// GCN: 2x GraphConv(norm='both') + leaky_relu + linear classifier.
// Interface (validated R6/R7): x/W/b f32, src/dst int32, out f32.
// R8: CSR entries carry (src, oi[src]) so no xscale pass; layer kernel
// batches 4 nodes/wave with W staged in LDS; full-occupancy grid.

__global__ void deg_kernel(const int* __restrict__ src, const int* __restrict__ dst,
                           int* dout, int* din, int e) {
    int i = blockIdx.x * blockDim.x + threadIdx.x;
    if (i < e) {
        atomicAdd(&dout[src[i]], 1);
        atomicAdd(&din[dst[i]], 1);
    }
}

__global__ void isq_kernel(const int* __restrict__ dout, const int* __restrict__ din,
                           float* oi, float* ii, int n) {
    int i = blockIdx.x * blockDim.x + threadIdx.x;
    if (i < n) {
        oi[i] = rsqrtf((float)max(dout[i], 1));
        ii[i] = rsqrtf((float)max(din[i], 1));
    }
}

// ---- exclusive prefix scan of deg_in -> row offsets ----
__global__ void scan1_kernel(const int* __restrict__ deg, int* row, int* partials, int n) {
    __shared__ int s[1024];
    int t = threadIdx.x;
    int i = blockIdx.x * 1024 + t;
    int v = (i < n) ? deg[i] : 0;
    s[t] = v;
    __syncthreads();
    for (int d = 1; d < 1024; d <<= 1) {
        int x = (t >= d) ? s[t - d] : 0;
        __syncthreads();
        s[t] += x;
        __syncthreads();
    }
    if (i < n) row[i] = s[t] - v;  // exclusive within chunk
    if (t == 1023) partials[blockIdx.x] = s[1023];
}

// parallel scan of chunk totals (nchunks <= 1024), single block
__global__ void scan2_kernel(int* partials, int nchunks, int* row, int n) {
    __shared__ int s[1024];
    int t = threadIdx.x;
    int v = (t < nchunks) ? partials[t] : 0;
    s[t] = v;
    __syncthreads();
    for (int d = 1; d < 1024; d <<= 1) {
        int x = (t >= d) ? s[t - d] : 0;
        __syncthreads();
        s[t] += x;
        __syncthreads();
    }
    if (t < nchunks) partials[t] = s[t] - v;  // exclusive
    if (t == nchunks - 1) row[n] = s[t];      // total == E
}

// add chunk bases; also init scatter cursor = row
__global__ void scan3_kernel(int* row, int* cursor, const int* __restrict__ partials, int n) {
    int i = blockIdx.x * blockDim.x + threadIdx.x;
    if (i < n) {
        int r = row[i] + partials[i >> 10];
        row[i] = r;
        cursor[i] = r;
    }
}

// csr2[p] = { src, oi[src] }  (cursor pre-initialized to row offsets)
__global__ void scatter_kernel(const int* __restrict__ src, const int* __restrict__ dst,
                               const float* __restrict__ oi, int* cursor, int2* csr2, int e) {
    int i = blockIdx.x * blockDim.x + threadIdx.x;
    if (i < e) {
        int s = src[i];
        int p = atomicAdd(&cursor[dst[i]], 1);
        csr2[p] = make_int2(s, __float_as_int(oi[s]));
    }
}

// One wave handles 4 nodes per iteration (grid-stride over groups).
// Lane = feature. W (64x64 f32) staged in LDS; per k, one ds_read serves 4
// fmas (one per node) with the aggregated rows broadcast via readlane.
template <bool FINAL>
__global__ __launch_bounds__(256) void layer_kernel(
    const float* __restrict__ feat, const int* __restrict__ row,
    const int2* __restrict__ csr2, const float* __restrict__ ii,
    const float* __restrict__ W, const float* __restrict__ bias,
    const float* __restrict__ Wc, const float* __restrict__ bcl,
    float* __restrict__ out, int n, int nwaves) {
    __shared__ float Ws[64 * 64];
    __shared__ float bs[64];
    int tid = threadIdx.x;
    for (int i = tid; i < 64 * 64; i += 256) Ws[i] = W[i];
    if (tid < 64) bs[tid] = bias[tid];
    __syncthreads();

    int lane = tid & 63;
    int wid = blockIdx.x * (blockDim.x >> 6) + (tid >> 6);
    float bl = bs[lane];
    float wc0 = 0.f, wc1 = 0.f, bc0 = 0.f, bc1 = 0.f;
    if constexpr (FINAL) {
        wc0 = Wc[lane * 2];
        wc1 = Wc[lane * 2 + 1];
        bc0 = bcl[0];
        bc1 = bcl[1];
    }

    int ngroups = (n + 3) >> 2;
    for (int g = wid; g < ngroups; g += nwaves) {
        int vbase = g << 2;
        int cnt = min(4, n - vbase);

        int r[5];
#pragma unroll
        for (int j = 0; j <= 4; j++) r[j] = row[vbase + min(j, cnt)];

        float acc[4];
#pragma unroll
        for (int j = 0; j < 4; j++) {
            float a = 0.f;
            int i = r[j], i1 = r[j + 1];
            for (; i + 3 < i1; i += 4) {  // 4 gathers in flight
                int2 e0 = csr2[i], e1 = csr2[i + 1], e2 = csr2[i + 2], e3 = csr2[i + 3];
                float f0 = feat[(size_t)e0.x * 64 + lane];
                float f1 = feat[(size_t)e1.x * 64 + lane];
                float f2 = feat[(size_t)e2.x * 64 + lane];
                float f3 = feat[(size_t)e3.x * 64 + lane];
                a = fmaf(f0, __int_as_float(e0.y), a);
                a = fmaf(f1, __int_as_float(e1.y), a);
                a = fmaf(f2, __int_as_float(e2.y), a);
                a = fmaf(f3, __int_as_float(e3.y), a);
            }
            for (; i < i1; i++) {
                int2 ee = csr2[i];
                a = fmaf(feat[(size_t)ee.x * 64 + lane], __int_as_float(ee.y), a);
            }
            acc[j] = a;
        }

        float t[4], o[4];
#pragma unroll
        for (int j = 0; j < 4; j++) {
            int vj = vbase + ((j < cnt) ? j : 0);
            t[j] = acc[j] * ii[vj];
            o[j] = bl;
        }
#pragma unroll
        for (int k = 0; k < 64; k++) {
            float w = Ws[k * 64 + lane];
#pragma unroll
            for (int j = 0; j < 4; j++) {
                float bk = __uint_as_float(
                    (unsigned)__builtin_amdgcn_readlane((int)__float_as_uint(t[j]), k));
                o[j] = fmaf(bk, w, o[j]);
            }
        }
#pragma unroll
        for (int j = 0; j < 4; j++) o[j] = (o[j] > 0.f) ? o[j] : 0.01f * o[j];

        if constexpr (!FINAL) {
            for (int j = 0; j < cnt; j++) out[(size_t)(vbase + j) * 64 + lane] = o[j];
        } else {
            for (int j = 0; j < cnt; j++) {
                float p0 = o[j] * wc0, p1 = o[j] * wc1;
#pragma unroll
                for (int off = 32; off; off >>= 1) {
                    p0 += __shfl_down(p0, off);
                    p1 += __shfl_down(p1, off);
                }
                if (lane == 0) ((float2*)out)[vbase + j] = make_float2(p0 + bc0, p1 + bc1);
            }
        }
    }
}

extern "C" void kernel_launch(void* const* d_in, const int* in_sizes, int n_in,
                              void* d_out, int out_size, void* d_ws, size_t ws_size,
                              hipStream_t stream) {
    const float* x  = (const float*)d_in[0];
    const int* src  = (const int*)d_in[1];
    const int* dst  = (const int*)d_in[2];
    const float* W1 = (const float*)d_in[3];
    const float* b1 = (const float*)d_in[4];
    const float* W2 = (const float*)d_in[5];
    const float* b2 = (const float*)d_in[6];
    const float* Wc = (const float*)d_in[7];
    const float* bc = (const float*)d_in[8];
    int n = in_sizes[0] / 64;
    int e = in_sizes[1];
    int total = n * 64;

    char* ws = (char*)d_ws;
    size_t off = 0;
    auto take = [&](size_t bytes) -> char* {
        char* p = ws + off;
        off = (off + bytes + 255) & ~(size_t)255;
        return p;
    };
    int* deg_out  = (int*)take((size_t)n * 4);
    int* deg_in   = (int*)take((size_t)n * 4);
    int* cursor   = (int*)take((size_t)n * 4);
    int* row      = (int*)take((size_t)(n + 1) * 4);
    int* partials = (int*)take(4096);
    int2* csr2    = (int2*)take((size_t)e * 8);        // 8 MB
    float* oi     = (float*)take((size_t)n * 4);
    float* ii     = (float*)take((size_t)n * 4);
    float* h1s    = (float*)take((size_t)total * 4);   // 25.6 MB

    const int tb = 256;
    // zero deg_out + deg_in (contiguous carve-outs)
    size_t zbytes = (size_t)((char*)deg_in + (size_t)n * 4 - (char*)deg_out);
    hipMemsetAsync(deg_out, 0, zbytes, stream);

    deg_kernel<<<(e + tb - 1) / tb, tb, 0, stream>>>(src, dst, deg_out, deg_in, e);
    isq_kernel<<<(n + tb - 1) / tb, tb, 0, stream>>>(deg_out, deg_in, oi, ii, n);

    int nchunks = (n + 1023) / 1024;
    scan1_kernel<<<nchunks, 1024, 0, stream>>>(deg_in, row, partials, n);
    scan2_kernel<<<1, 1024, 0, stream>>>(partials, nchunks, row, n);
    scan3_kernel<<<(n + tb - 1) / tb, tb, 0, stream>>>(row, cursor, partials, n);
    scatter_kernel<<<(e + tb - 1) / tb, tb, 0, stream>>>(src, dst, oi, cursor, csr2, e);

    const int lblocks = 2048;                  // 8192 waves = full occupancy
    const int nwaves = lblocks * (tb / 64);
    layer_kernel<false><<<lblocks, tb, 0, stream>>>(x, row, csr2, ii, W1, b1,
                                                    nullptr, nullptr, h1s, n, nwaves);
    layer_kernel<true><<<lblocks, tb, 0, stream>>>(h1s, row, csr2, ii, W2, b2,
                                                   Wc, bc, (float*)d_out, n, nwaves);
}

// Round 9
// 416.165 us; speedup vs baseline: 1.2992x; 1.2992x over previous
//
#include <hip/hip_runtime.h>

// GCN: 2x GraphConv(norm='both') + leaky_relu + linear classifier.
// Interface (validated R6/R7): x/W/b f32, src/dst int32, out f32.
// R9 = R7 layer structure (lean VGPR, no LDS, wave-per-node) + full grid
// (2048 blocks), oi folded into CSR entries (no xscale pass), parallel scan2.
// R8 lesson: latency-bound gather => resident waves are king; don't fatten.

__global__ void deg_kernel(const int* __restrict__ src, const int* __restrict__ dst,
                           int* dout, int* din, int e) {
    int i = blockIdx.x * blockDim.x + threadIdx.x;
    if (i < e) {
        atomicAdd(&dout[src[i]], 1);
        atomicAdd(&din[dst[i]], 1);
    }
}

__global__ void isq_kernel(const int* __restrict__ dout, const int* __restrict__ din,
                           float* oi, float* ii, int n) {
    int i = blockIdx.x * blockDim.x + threadIdx.x;
    if (i < n) {
        oi[i] = rsqrtf((float)max(dout[i], 1));
        ii[i] = rsqrtf((float)max(din[i], 1));
    }
}

// ---- exclusive prefix scan of deg_in -> row offsets ----
__global__ void scan1_kernel(const int* __restrict__ deg, int* row, int* partials, int n) {
    __shared__ int s[1024];
    int t = threadIdx.x;
    int i = blockIdx.x * 1024 + t;
    int v = (i < n) ? deg[i] : 0;
    s[t] = v;
    __syncthreads();
    for (int d = 1; d < 1024; d <<= 1) {
        int x = (t >= d) ? s[t - d] : 0;
        __syncthreads();
        s[t] += x;
        __syncthreads();
    }
    if (i < n) row[i] = s[t] - v;  // exclusive within chunk
    if (t == 1023) partials[blockIdx.x] = s[1023];
}

// parallel scan of chunk totals (nchunks <= 1024), single block
__global__ void scan2_kernel(int* partials, int nchunks, int* row, int n) {
    __shared__ int s[1024];
    int t = threadIdx.x;
    int v = (t < nchunks) ? partials[t] : 0;
    s[t] = v;
    __syncthreads();
    for (int d = 1; d < 1024; d <<= 1) {
        int x = (t >= d) ? s[t - d] : 0;
        __syncthreads();
        s[t] += x;
        __syncthreads();
    }
    if (t < nchunks) partials[t] = s[t] - v;  // exclusive
    if (t == nchunks - 1) row[n] = s[t];      // total == E
}

// add chunk bases; also init scatter cursor = row
__global__ void scan3_kernel(int* row, int* cursor, const int* __restrict__ partials, int n) {
    int i = blockIdx.x * blockDim.x + threadIdx.x;
    if (i < n) {
        int r = row[i] + partials[i >> 10];
        row[i] = r;
        cursor[i] = r;
    }
}

// csr2[p] = { src, oi[src] }  (cursor pre-initialized to row offsets)
__global__ void scatter_kernel(const int* __restrict__ src, const int* __restrict__ dst,
                               const float* __restrict__ oi, int* cursor, int2* csr2, int e) {
    int i = blockIdx.x * blockDim.x + threadIdx.x;
    if (i < e) {
        int s = src[i];
        int p = atomicAdd(&cursor[dst[i]], 1);
        csr2[p] = make_int2(s, __float_as_int(oi[s]));
    }
}

// One wave per node (grid-stride). Lane = feature. Gather with per-edge
// oi weight (folded in csr2); matvec via readlane broadcast (W hits L1).
template <bool FINAL>
__global__ __launch_bounds__(256) void layer_kernel(
    const float* __restrict__ feat, const int* __restrict__ row,
    const int2* __restrict__ csr2, const float* __restrict__ ii,
    const float* __restrict__ W, const float* __restrict__ bias,
    const float* __restrict__ Wc, const float* __restrict__ bcl,
    float* __restrict__ out, int n, int nwaves) {
    int lane = threadIdx.x & 63;
    int wid = blockIdx.x * (blockDim.x >> 6) + (threadIdx.x >> 6);

    float wreg[64];
#pragma unroll
    for (int k = 0; k < 64; k++) wreg[k] = W[k * 64 + lane];  // column `lane`
    float bl = bias[lane];
    float wc0 = 0.f, wc1 = 0.f, bc0 = 0.f, bc1 = 0.f;
    if constexpr (FINAL) {
        wc0 = Wc[lane * 2];
        wc1 = Wc[lane * 2 + 1];
        bc0 = bcl[0];
        bc1 = bcl[1];
    }

    for (int v = wid; v < n; v += nwaves) {
        int s0 = row[v], s1 = row[v + 1];
        float acc = 0.f;
        int i = s0;
        for (; i + 3 < s1; i += 4) {  // 4 gathers in flight
            int2 e0 = csr2[i], e1 = csr2[i + 1], e2 = csr2[i + 2], e3 = csr2[i + 3];
            float f0 = feat[(size_t)e0.x * 64 + lane];
            float f1 = feat[(size_t)e1.x * 64 + lane];
            float f2 = feat[(size_t)e2.x * 64 + lane];
            float f3 = feat[(size_t)e3.x * 64 + lane];
            acc = fmaf(f0, __int_as_float(e0.y), acc);
            acc = fmaf(f1, __int_as_float(e1.y), acc);
            acc = fmaf(f2, __int_as_float(e2.y), acc);
            acc = fmaf(f3, __int_as_float(e3.y), acc);
        }
        for (; i < s1; i++) {
            int2 ee = csr2[i];
            acc = fmaf(feat[(size_t)ee.x * 64 + lane], __int_as_float(ee.y), acc);
        }

        float t = acc * ii[v];  // lane k holds aggregated row element k
        float o = bl;
#pragma unroll
        for (int k = 0; k < 64; k++) {
            float bk = __uint_as_float(
                (unsigned)__builtin_amdgcn_readlane((int)__float_as_uint(t), k));
            o = fmaf(bk, wreg[k], o);
        }
        o = (o > 0.f) ? o : 0.01f * o;  // leaky relu

        if constexpr (!FINAL) {
            out[(size_t)v * 64 + lane] = o;
        } else {
            float p0 = o * wc0, p1 = o * wc1;
#pragma unroll
            for (int off = 32; off; off >>= 1) {
                p0 += __shfl_down(p0, off);
                p1 += __shfl_down(p1, off);
            }
            if (lane == 0) ((float2*)out)[v] = make_float2(p0 + bc0, p1 + bc1);
        }
    }
}

extern "C" void kernel_launch(void* const* d_in, const int* in_sizes, int n_in,
                              void* d_out, int out_size, void* d_ws, size_t ws_size,
                              hipStream_t stream) {
    const float* x  = (const float*)d_in[0];
    const int* src  = (const int*)d_in[1];
    const int* dst  = (const int*)d_in[2];
    const float* W1 = (const float*)d_in[3];
    const float* b1 = (const float*)d_in[4];
    const float* W2 = (const float*)d_in[5];
    const float* b2 = (const float*)d_in[6];
    const float* Wc = (const float*)d_in[7];
    const float* bc = (const float*)d_in[8];
    int n = in_sizes[0] / 64;
    int e = in_sizes[1];
    int total = n * 64;

    char* ws = (char*)d_ws;
    size_t off = 0;
    auto take = [&](size_t bytes) -> char* {
        char* p = ws + off;
        off = (off + bytes + 255) & ~(size_t)255;
        return p;
    };
    int* deg_out  = (int*)take((size_t)n * 4);
    int* deg_in   = (int*)take((size_t)n * 4);
    int* cursor   = (int*)take((size_t)n * 4);
    int* row      = (int*)take((size_t)(n + 1) * 4);
    int* partials = (int*)take(4096);
    int2* csr2    = (int2*)take((size_t)e * 8);        // 8 MB
    float* oi     = (float*)take((size_t)n * 4);
    float* ii     = (float*)take((size_t)n * 4);
    float* h1s    = (float*)take((size_t)total * 4);   // 25.6 MB

    const int tb = 256;
    // zero deg_out + deg_in (contiguous carve-outs)
    size_t zbytes = (size_t)((char*)deg_in + (size_t)n * 4 - (char*)deg_out);
    hipMemsetAsync(deg_out, 0, zbytes, stream);

    deg_kernel<<<(e + tb - 1) / tb, tb, 0, stream>>>(src, dst, deg_out, deg_in, e);
    isq_kernel<<<(n + tb - 1) / tb, tb, 0, stream>>>(deg_out, deg_in, oi, ii, n);

    int nchunks = (n + 1023) / 1024;
    scan1_kernel<<<nchunks, 1024, 0, stream>>>(deg_in, row, partials, n);
    scan2_kernel<<<1, 1024, 0, stream>>>(partials, nchunks, row, n);
    scan3_kernel<<<(n + tb - 1) / tb, tb, 0, stream>>>(row, cursor, partials, n);
    scatter_kernel<<<(e + tb - 1) / tb, tb, 0, stream>>>(src, dst, oi, cursor, csr2, e);

    const int lblocks = 2048;                  // 8192 waves = full slot count
    const int nwaves = lblocks * (tb / 64);
    layer_kernel<false><<<lblocks, tb, 0, stream>>>(x, row, csr2, ii, W1, b1,
                                                    nullptr, nullptr, h1s, n, nwaves);
    layer_kernel<true><<<lblocks, tb, 0, stream>>>(h1s, row, csr2, ii, W2, b2,
                                                   Wc, bc, (float*)d_out, n, nwaves);
}